// Round 1
// baseline (466.343 us; speedup 1.0000x reference)
//
#include <hip/hip_runtime.h>
#include <math.h>

#define N_NODES 100000
#define N_EDGES 1600000
#define IN_DIM 128
#define HEADS 4
#define OUT_DIM 32
#define HD 128  // HEADS*OUT_DIM
#define NEG_SLOPE 0.2f
#define SCAN_NBLK 98  // ceil(100000/1024)

// ---------------- K1: x_proj = x @ W^T (fp32, LDS tiled) ----------------
// Block: 64 rows x 128 cols, BK=32, 256 threads, thread tile 4 rows x 8 cols.
__global__ __launch_bounds__(256) void k_gemm(const float* __restrict__ x,
                                              const float* __restrict__ W,
                                              float* __restrict__ xp) {
    __shared__ float xs[64 * 33];
    __shared__ float ws[32 * 128];
    const int tid = threadIdx.x;
    const int tx = tid & 15;   // col group: cols {4tx..4tx+3} and {64+4tx..}
    const int ty = tid >> 4;   // row group [0,16): rows ty*4..ty*4+3
    const long row_base = (long)blockIdx.x * 64;

    float acc[4][8];
#pragma unroll
    for (int i = 0; i < 4; i++)
#pragma unroll
        for (int j = 0; j < 8; j++) acc[i][j] = 0.f;

    for (int kt = 0; kt < 4; kt++) {
        const int k0 = kt * 32;
        // stage x tile 64x32
        {
            int r = tid >> 2;
            int kg = (tid & 3) * 8;
            long row = row_base + r;
            float4 a, b;
            if (row < N_NODES) {
                const float* p = x + row * IN_DIM + k0 + kg;
                a = *(const float4*)(p);
                b = *(const float4*)(p + 4);
            } else {
                a = make_float4(0.f, 0.f, 0.f, 0.f);
                b = a;
            }
            float* d = &xs[r * 33 + kg];
            d[0] = a.x; d[1] = a.y; d[2] = a.z; d[3] = a.w;
            d[4] = b.x; d[5] = b.y; d[6] = b.z; d[7] = b.w;
        }
        // stage W tile transposed: ws[k][c]
        {
            int c = tid >> 1;
            int kh = (tid & 1) * 16;
            const float* p = W + c * IN_DIM + k0 + kh;
#pragma unroll
            for (int i = 0; i < 4; i++) {
                float4 v = *(const float4*)(p + 4 * i);
                ws[(kh + 4 * i + 0) * 128 + c] = v.x;
                ws[(kh + 4 * i + 1) * 128 + c] = v.y;
                ws[(kh + 4 * i + 2) * 128 + c] = v.z;
                ws[(kh + 4 * i + 3) * 128 + c] = v.w;
            }
        }
        __syncthreads();
#pragma unroll
        for (int k = 0; k < 32; k++) {
            float xv[4];
#pragma unroll
            for (int i = 0; i < 4; i++) xv[i] = xs[(ty * 4 + i) * 33 + k];
            float4 w0 = *(const float4*)&ws[k * 128 + 4 * tx];
            float4 w1 = *(const float4*)&ws[k * 128 + 64 + 4 * tx];
#pragma unroll
            for (int i = 0; i < 4; i++) {
                acc[i][0] += xv[i] * w0.x; acc[i][1] += xv[i] * w0.y;
                acc[i][2] += xv[i] * w0.z; acc[i][3] += xv[i] * w0.w;
                acc[i][4] += xv[i] * w1.x; acc[i][5] += xv[i] * w1.y;
                acc[i][6] += xv[i] * w1.z; acc[i][7] += xv[i] * w1.w;
            }
        }
        __syncthreads();
    }
#pragma unroll
    for (int i = 0; i < 4; i++) {
        long row = row_base + ty * 4 + i;
        if (row < N_NODES) {
            float4 o0 = make_float4(acc[i][0], acc[i][1], acc[i][2], acc[i][3]);
            float4 o1 = make_float4(acc[i][4], acc[i][5], acc[i][6], acc[i][7]);
            *(float4*)(xp + row * HD + 4 * tx) = o0;
            *(float4*)(xp + row * HD + 64 + 4 * tx) = o1;
        }
    }
}

// ---------------- K1b: per-node attention dots ----------------
__global__ __launch_bounds__(256) void k_attdots(const float* __restrict__ xp,
                                                 const float* __restrict__ att_src,
                                                 const float* __restrict__ att_dst,
                                                 float* __restrict__ asrc,
                                                 float* __restrict__ adst) {
    int t = blockIdx.x * 256 + threadIdx.x;
    if (t >= N_NODES * HEADS) return;
    int h = t & 3;
    int n = t >> 2;
    const float* row = xp + (long)n * HD + h * OUT_DIM;
    const float* as = att_src + h * OUT_DIM;
    const float* ad = att_dst + h * OUT_DIM;
    float s0 = 0.f, s1 = 0.f;
#pragma unroll
    for (int d = 0; d < OUT_DIM; d += 4) {
        float4 v = *(const float4*)(row + d);
        float4 a = *(const float4*)(as + d);
        float4 b = *(const float4*)(ad + d);
        s0 += v.x * a.x + v.y * a.y + v.z * a.z + v.w * a.w;
        s1 += v.x * b.x + v.y * b.y + v.z * b.z + v.w * b.w;
    }
    asrc[t] = s0;
    adst[t] = s1;
}

// ---------------- K2: per-dst edge counts ----------------
__global__ void k_count(const int* __restrict__ ei, int* __restrict__ cnt) {
    int e = blockIdx.x * 256 + threadIdx.x;
    if (e < N_EDGES) atomicAdd(&cnt[ei[N_EDGES + e]], 1);
}

// ---------------- K3: exclusive scan of counts (3 kernels) ----------------
__global__ __launch_bounds__(256) void k_scan1(const int* __restrict__ cnt,
                                               int* __restrict__ row_start,
                                               int* __restrict__ partial) {
    __shared__ int lds[256];
    int t = threadIdx.x;
    int base = blockIdx.x * 1024 + t * 4;
    int c0 = (base + 0 < N_NODES) ? cnt[base + 0] : 0;
    int c1 = (base + 1 < N_NODES) ? cnt[base + 1] : 0;
    int c2 = (base + 2 < N_NODES) ? cnt[base + 2] : 0;
    int c3 = (base + 3 < N_NODES) ? cnt[base + 3] : 0;
    int p1 = c0, p2 = c0 + c1, p3 = c0 + c1 + c2;
    int tsum = p3 + c3;
    lds[t] = tsum;
    __syncthreads();
    for (int off = 1; off < 256; off <<= 1) {
        int v = (t >= off) ? lds[t - off] : 0;
        __syncthreads();
        lds[t] += v;
        __syncthreads();
    }
    int excl = (t == 0) ? 0 : lds[t - 1];
    if (base + 0 < N_NODES) row_start[base + 0] = excl;
    if (base + 1 < N_NODES) row_start[base + 1] = excl + p1;
    if (base + 2 < N_NODES) row_start[base + 2] = excl + p2;
    if (base + 3 < N_NODES) row_start[base + 3] = excl + p3;
    if (t == 255) partial[blockIdx.x] = lds[255];
}

__global__ __launch_bounds__(128) void k_scan2(int* __restrict__ partial) {
    __shared__ int lds[128];
    int t = threadIdx.x;
    int v = (t < SCAN_NBLK) ? partial[t] : 0;
    lds[t] = v;
    __syncthreads();
    for (int off = 1; off < 128; off <<= 1) {
        int u = (t >= off) ? lds[t - off] : 0;
        __syncthreads();
        lds[t] += u;
        __syncthreads();
    }
    if (t < SCAN_NBLK) partial[t] = (t == 0) ? 0 : lds[t - 1];
}

__global__ void k_scan3(int* __restrict__ row_start, const int* __restrict__ partial,
                        int* __restrict__ cursor) {
    int i = blockIdx.x * 256 + threadIdx.x;
    if (i < N_NODES) {
        int rs = row_start[i] + partial[i >> 10];
        row_start[i] = rs;
        cursor[i] = rs;
    }
    if (i == 0) row_start[N_NODES] = N_EDGES;
}

// ---------------- K4: attention logits + CSR scatter ----------------
__global__ void k_scatter(const int* __restrict__ ei,
                          const float4* __restrict__ asrc4,
                          const float4* __restrict__ adst4,
                          int* __restrict__ cursor,
                          int* __restrict__ esrc,
                          float4* __restrict__ att4) {
    int e = blockIdx.x * 256 + threadIdx.x;
    if (e >= N_EDGES) return;
    int s = ei[e];
    int d = ei[N_EDGES + e];
    float4 a = asrc4[s];
    float4 b = adst4[d];
    float4 t;
    t.x = a.x + b.x; t.y = a.y + b.y; t.z = a.z + b.z; t.w = a.w + b.w;
    t.x = (t.x >= 0.f) ? t.x : NEG_SLOPE * t.x;
    t.y = (t.y >= 0.f) ? t.y : NEG_SLOPE * t.y;
    t.z = (t.z >= 0.f) ? t.z : NEG_SLOPE * t.z;
    t.w = (t.w >= 0.f) ? t.w : NEG_SLOPE * t.w;
    int pos = atomicAdd(&cursor[d], 1);
    esrc[pos] = s;
    att4[pos] = t;
}

// ---------------- K5: per-node softmax + aggregation (1 wave/node) ----------------
__global__ __launch_bounds__(256) void k_aggregate(const int* __restrict__ row_start,
                                                   const int* __restrict__ esrc,
                                                   const float4* __restrict__ att4,
                                                   const float* __restrict__ xp,
                                                   const float* __restrict__ bias,
                                                   float* __restrict__ out) {
    const int wid = threadIdx.x >> 6;
    const int lane = threadIdx.x & 63;
    const int n = blockIdx.x * 4 + wid;
    if (n >= N_NODES) return;
    const int s0 = row_start[n];
    const int s1 = row_start[n + 1];
    const bool hi = lane >= 32;

    // phase 1: per-head running max (wave-uniform loads; every lane sees all edges)
    float m0 = -1e30f, m1 = -1e30f;
    for (int j = s0; j < s1; j++) {
        float4 a = att4[j];
        float a0 = hi ? a.y : a.x;
        float a1 = hi ? a.w : a.z;
        m0 = fmaxf(m0, a0);
        m1 = fmaxf(m1, a1);
    }
    // phase 2: exp-weighted accumulation; lane covers elements {lane, 64+lane}
    float acc0 = 0.f, acc1 = 0.f, den0 = 0.f, den1 = 0.f;
    for (int j = s0; j < s1; j++) {
        float4 a = att4[j];
        float a0 = hi ? a.y : a.x;
        float a1 = hi ? a.w : a.z;
        float e0 = __expf(a0 - m0);
        float e1 = __expf(a1 - m1);
        den0 += e0;
        den1 += e1;
        const float* row = xp + (long)esrc[j] * HD;
        acc0 += e0 * row[lane];
        acc1 += e1 * row[64 + lane];
    }
    out[(long)n * HD + lane] = acc0 / (den0 + 1e-12f) + bias[lane];
    out[(long)n * HD + 64 + lane] = acc1 / (den1 + 1e-12f) + bias[64 + lane];
}

extern "C" void kernel_launch(void* const* d_in, const int* in_sizes, int n_in,
                              void* d_out, int out_size, void* d_ws, size_t ws_size,
                              hipStream_t stream) {
    const float* x = (const float*)d_in[0];
    const int* ei = (const int*)d_in[1];
    const float* W = (const float*)d_in[2];
    const float* att_src = (const float*)d_in[3];
    const float* att_dst = (const float*)d_in[4];
    const float* bias = (const float*)d_in[5];
    float* out = (float*)d_out;
    char* ws = (char*)d_ws;

    // workspace layout (bytes), all 16B-aligned
    float* xp        = (float*)(ws + 0);          // 51,200,000
    float* asrc      = (float*)(ws + 51200000);   //  1,600,000
    float* adst      = (float*)(ws + 52800000);   //  1,600,000
    float4* att4     = (float4*)(ws + 54400000);  // 25,600,000
    int* esrc        = (int*)(ws + 80000000);     //  6,400,000
    int* cnt         = (int*)(ws + 86400000);     //    400,000
    int* row_start   = (int*)(ws + 86800000);     //    400,004
    int* cursor      = (int*)(ws + 87200256);     //    400,000
    int* partial     = (int*)(ws + 87600256);     //        512
    // total ~87.6 MB

    hipMemsetAsync(cnt, 0, N_NODES * sizeof(int), stream);
    k_gemm<<<(N_NODES + 63) / 64, 256, 0, stream>>>(x, W, xp);
    k_attdots<<<(N_NODES * HEADS + 255) / 256, 256, 0, stream>>>(xp, att_src, att_dst, asrc, adst);
    k_count<<<(N_EDGES + 255) / 256, 256, 0, stream>>>(ei, cnt);
    k_scan1<<<SCAN_NBLK, 256, 0, stream>>>(cnt, row_start, partial);
    k_scan2<<<1, 128, 0, stream>>>(partial);
    k_scan3<<<(N_NODES + 255) / 256, 256, 0, stream>>>(row_start, partial, cursor);
    k_scatter<<<(N_EDGES + 255) / 256, 256, 0, stream>>>(ei, (const float4*)asrc, (const float4*)adst, cursor, esrc, att4);
    k_aggregate<<<(N_NODES + 3) / 4, 256, 0, stream>>>(row_start, esrc, att4, xp, bias, out);
}

// Round 2
// 349.269 us; speedup vs baseline: 1.3352x; 1.3352x over previous
//
#include <hip/hip_runtime.h>
#include <math.h>

#define N_NODES 100000
#define N_EDGES 1600000
#define IN_DIM 128
#define HEADS 4
#define OUT_DIM 32
#define HD 128  // HEADS*OUT_DIM
#define NEG_SLOPE 0.2f
#define SCAN_NBLK 98  // ceil(100000/1024)

// ---------------- K1: x_proj = x @ W^T (fp32, LDS tiled) ----------------
// Block: 64 rows x 128 cols, BK=32, 256 threads, thread tile 4 rows x 8 cols.
__global__ __launch_bounds__(256) void k_gemm(const float* __restrict__ x,
                                              const float* __restrict__ W,
                                              float* __restrict__ xp) {
    __shared__ float xs[64 * 33];
    __shared__ float ws[32 * 128];
    const int tid = threadIdx.x;
    const int tx = tid & 15;   // col group: cols {4tx..4tx+3} and {64+4tx..}
    const int ty = tid >> 4;   // row group [0,16): rows ty*4..ty*4+3
    const long row_base = (long)blockIdx.x * 64;

    float acc[4][8];
#pragma unroll
    for (int i = 0; i < 4; i++)
#pragma unroll
        for (int j = 0; j < 8; j++) acc[i][j] = 0.f;

    for (int kt = 0; kt < 4; kt++) {
        const int k0 = kt * 32;
        // stage x tile 64x32
        {
            int r = tid >> 2;
            int kg = (tid & 3) * 8;
            long row = row_base + r;
            float4 a, b;
            if (row < N_NODES) {
                const float* p = x + row * IN_DIM + k0 + kg;
                a = *(const float4*)(p);
                b = *(const float4*)(p + 4);
            } else {
                a = make_float4(0.f, 0.f, 0.f, 0.f);
                b = a;
            }
            float* d = &xs[r * 33 + kg];
            d[0] = a.x; d[1] = a.y; d[2] = a.z; d[3] = a.w;
            d[4] = b.x; d[5] = b.y; d[6] = b.z; d[7] = b.w;
        }
        // stage W tile transposed: ws[k][c]
        {
            int c = tid >> 1;
            int kh = (tid & 1) * 16;
            const float* p = W + c * IN_DIM + k0 + kh;
#pragma unroll
            for (int i = 0; i < 4; i++) {
                float4 v = *(const float4*)(p + 4 * i);
                ws[(kh + 4 * i + 0) * 128 + c] = v.x;
                ws[(kh + 4 * i + 1) * 128 + c] = v.y;
                ws[(kh + 4 * i + 2) * 128 + c] = v.z;
                ws[(kh + 4 * i + 3) * 128 + c] = v.w;
            }
        }
        __syncthreads();
#pragma unroll
        for (int k = 0; k < 32; k++) {
            float xv[4];
#pragma unroll
            for (int i = 0; i < 4; i++) xv[i] = xs[(ty * 4 + i) * 33 + k];
            float4 w0 = *(const float4*)&ws[k * 128 + 4 * tx];
            float4 w1 = *(const float4*)&ws[k * 128 + 64 + 4 * tx];
#pragma unroll
            for (int i = 0; i < 4; i++) {
                acc[i][0] += xv[i] * w0.x; acc[i][1] += xv[i] * w0.y;
                acc[i][2] += xv[i] * w0.z; acc[i][3] += xv[i] * w0.w;
                acc[i][4] += xv[i] * w1.x; acc[i][5] += xv[i] * w1.y;
                acc[i][6] += xv[i] * w1.z; acc[i][7] += xv[i] * w1.w;
            }
        }
        __syncthreads();
    }
#pragma unroll
    for (int i = 0; i < 4; i++) {
        long row = row_base + ty * 4 + i;
        if (row < N_NODES) {
            float4 o0 = make_float4(acc[i][0], acc[i][1], acc[i][2], acc[i][3]);
            float4 o1 = make_float4(acc[i][4], acc[i][5], acc[i][6], acc[i][7]);
            *(float4*)(xp + row * HD + 4 * tx) = o0;
            *(float4*)(xp + row * HD + 64 + 4 * tx) = o1;
        }
    }
}

// ---------------- K1b: per-node attention dots ----------------
__global__ __launch_bounds__(256) void k_attdots(const float* __restrict__ xp,
                                                 const float* __restrict__ att_src,
                                                 const float* __restrict__ att_dst,
                                                 float* __restrict__ asrc,
                                                 float* __restrict__ adst) {
    int t = blockIdx.x * 256 + threadIdx.x;
    if (t >= N_NODES * HEADS) return;
    int h = t & 3;
    int n = t >> 2;
    const float* row = xp + (long)n * HD + h * OUT_DIM;
    const float* as = att_src + h * OUT_DIM;
    const float* ad = att_dst + h * OUT_DIM;
    float s0 = 0.f, s1 = 0.f;
#pragma unroll
    for (int d = 0; d < OUT_DIM; d += 4) {
        float4 v = *(const float4*)(row + d);
        float4 a = *(const float4*)(as + d);
        float4 b = *(const float4*)(ad + d);
        s0 += v.x * a.x + v.y * a.y + v.z * a.z + v.w * a.w;
        s1 += v.x * b.x + v.y * b.y + v.z * b.z + v.w * b.w;
    }
    asrc[t] = s0;
    adst[t] = s1;
}

// ---------------- K2: per-dst edge counts ----------------
__global__ void k_count(const int* __restrict__ ei, int* __restrict__ cnt) {
    int e = blockIdx.x * 256 + threadIdx.x;
    if (e < N_EDGES) atomicAdd(&cnt[ei[N_EDGES + e]], 1);
}

// ---------------- K3: exclusive scan of counts (3 kernels) ----------------
__global__ __launch_bounds__(256) void k_scan1(const int* __restrict__ cnt,
                                               int* __restrict__ row_start,
                                               int* __restrict__ partial) {
    __shared__ int lds[256];
    int t = threadIdx.x;
    int base = blockIdx.x * 1024 + t * 4;
    int c0 = (base + 0 < N_NODES) ? cnt[base + 0] : 0;
    int c1 = (base + 1 < N_NODES) ? cnt[base + 1] : 0;
    int c2 = (base + 2 < N_NODES) ? cnt[base + 2] : 0;
    int c3 = (base + 3 < N_NODES) ? cnt[base + 3] : 0;
    int p1 = c0, p2 = c0 + c1, p3 = c0 + c1 + c2;
    int tsum = p3 + c3;
    lds[t] = tsum;
    __syncthreads();
    for (int off = 1; off < 256; off <<= 1) {
        int v = (t >= off) ? lds[t - off] : 0;
        __syncthreads();
        lds[t] += v;
        __syncthreads();
    }
    int excl = (t == 0) ? 0 : lds[t - 1];
    if (base + 0 < N_NODES) row_start[base + 0] = excl;
    if (base + 1 < N_NODES) row_start[base + 1] = excl + p1;
    if (base + 2 < N_NODES) row_start[base + 2] = excl + p2;
    if (base + 3 < N_NODES) row_start[base + 3] = excl + p3;
    if (t == 255) partial[blockIdx.x] = lds[255];
}

__global__ __launch_bounds__(128) void k_scan2(int* __restrict__ partial) {
    __shared__ int lds[128];
    int t = threadIdx.x;
    int v = (t < SCAN_NBLK) ? partial[t] : 0;
    lds[t] = v;
    __syncthreads();
    for (int off = 1; off < 128; off <<= 1) {
        int u = (t >= off) ? lds[t - off] : 0;
        __syncthreads();
        lds[t] += u;
        __syncthreads();
    }
    if (t < SCAN_NBLK) partial[t] = (t == 0) ? 0 : lds[t - 1];
}

__global__ void k_scan3(int* __restrict__ row_start, const int* __restrict__ partial,
                        int* __restrict__ cursor) {
    int i = blockIdx.x * 256 + threadIdx.x;
    if (i < N_NODES) {
        int rs = row_start[i] + partial[i >> 10];
        row_start[i] = rs;
        cursor[i] = rs;
    }
    if (i == 0) row_start[N_NODES] = N_EDGES;
}

// ---------------- K4: attention logits + CSR scatter ----------------
__global__ void k_scatter(const int* __restrict__ ei,
                          const float4* __restrict__ asrc4,
                          const float4* __restrict__ adst4,
                          int* __restrict__ cursor,
                          int* __restrict__ esrc,
                          float4* __restrict__ att4) {
    int e = blockIdx.x * 256 + threadIdx.x;
    if (e >= N_EDGES) return;
    int s = ei[e];
    int d = ei[N_EDGES + e];
    float4 a = asrc4[s];
    float4 b = adst4[d];
    float4 t;
    t.x = a.x + b.x; t.y = a.y + b.y; t.z = a.z + b.z; t.w = a.w + b.w;
    t.x = (t.x >= 0.f) ? t.x : NEG_SLOPE * t.x;
    t.y = (t.y >= 0.f) ? t.y : NEG_SLOPE * t.y;
    t.z = (t.z >= 0.f) ? t.z : NEG_SLOPE * t.z;
    t.w = (t.w >= 0.f) ? t.w : NEG_SLOPE * t.w;
    int pos = atomicAdd(&cursor[d], 1);
    esrc[pos] = s;
    att4[pos] = t;
}

// ---------------- K5: single-pass softmax + aggregation (1 wave/node) ----------------
// Softmax computed WITHOUT the max-shift (shift-invariant; logits bounded,
// clamped at 80 for absolute overflow safety). Edge metadata (esrc, att4) is
// loaded once per 64-edge chunk with one coalesced lane-parallel load, then
// broadcast per-edge via __shfl. Gather loop unrolled x4 -> 8 independent
// 256B gathers in flight per wave, breaking the per-edge latency chain.
__global__ __launch_bounds__(256) void k_aggregate(const int* __restrict__ row_start,
                                                   const int* __restrict__ esrc,
                                                   const float4* __restrict__ att4,
                                                   const float* __restrict__ xp,
                                                   const float* __restrict__ bias,
                                                   float* __restrict__ out) {
    const int wid = threadIdx.x >> 6;
    const int lane = threadIdx.x & 63;
    const int n = blockIdx.x * 4 + wid;
    if (n >= N_NODES) return;
    const int s0 = row_start[n];
    const int s1 = row_start[n + 1];
    const bool hi = lane >= 32;

    float acc0 = 0.f, acc1 = 0.f, den0 = 0.f, den1 = 0.f;

    for (int base = s0; base < s1; base += 64) {
        const int rem = s1 - base;
        const int cnt = rem < 64 ? rem : 64;
        const bool v = lane < cnt;
        int msrc = v ? esrc[base + lane] : 0;
        float4 ma = v ? att4[base + lane] : make_float4(-1e30f, -1e30f, -1e30f, -1e30f);
        // per-owner-lane unnormalized softmax weights (exp without shift)
        float wx = __expf(fminf(ma.x, 80.f));
        float wy = __expf(fminf(ma.y, 80.f));
        float wz = __expf(fminf(ma.z, 80.f));
        float ww = __expf(fminf(ma.w, 80.f));

        int j = 0;
        for (; j + 4 <= cnt; j += 4) {
            const float* r[4];
            float e0[4], e1[4];
#pragma unroll
            for (int u = 0; u < 4; u++) {
                int src = __shfl(msrc, j + u);
                float a = __shfl(wx, j + u);
                float b = __shfl(wy, j + u);
                float c = __shfl(wz, j + u);
                float d = __shfl(ww, j + u);
                e0[u] = hi ? b : a;
                e1[u] = hi ? d : c;
                r[u] = xp + (long)src * HD;
            }
            float g0[4], g1[4];
#pragma unroll
            for (int u = 0; u < 4; u++) {
                g0[u] = r[u][lane];
                g1[u] = r[u][64 + lane];
            }
#pragma unroll
            for (int u = 0; u < 4; u++) {
                den0 += e0[u];
                den1 += e1[u];
                acc0 = fmaf(e0[u], g0[u], acc0);
                acc1 = fmaf(e1[u], g1[u], acc1);
            }
        }
        for (; j < cnt; j++) {
            int src = __shfl(msrc, j);
            float a = __shfl(wx, j);
            float b = __shfl(wy, j);
            float c = __shfl(wz, j);
            float d = __shfl(ww, j);
            float e0s = hi ? b : a;
            float e1s = hi ? d : c;
            const float* r = xp + (long)src * HD;
            den0 += e0s;
            den1 += e1s;
            acc0 = fmaf(e0s, r[lane], acc0);
            acc1 = fmaf(e1s, r[64 + lane], acc1);
        }
    }
    out[(long)n * HD + lane] = acc0 / (den0 + 1e-12f) + bias[lane];
    out[(long)n * HD + 64 + lane] = acc1 / (den1 + 1e-12f) + bias[64 + lane];
}

extern "C" void kernel_launch(void* const* d_in, const int* in_sizes, int n_in,
                              void* d_out, int out_size, void* d_ws, size_t ws_size,
                              hipStream_t stream) {
    const float* x = (const float*)d_in[0];
    const int* ei = (const int*)d_in[1];
    const float* W = (const float*)d_in[2];
    const float* att_src = (const float*)d_in[3];
    const float* att_dst = (const float*)d_in[4];
    const float* bias = (const float*)d_in[5];
    float* out = (float*)d_out;
    char* ws = (char*)d_ws;

    // workspace layout (bytes), all 16B-aligned
    float* xp        = (float*)(ws + 0);          // 51,200,000
    float* asrc      = (float*)(ws + 51200000);   //  1,600,000
    float* adst      = (float*)(ws + 52800000);   //  1,600,000
    float4* att4     = (float4*)(ws + 54400000);  // 25,600,000
    int* esrc        = (int*)(ws + 80000000);     //  6,400,000
    int* cnt         = (int*)(ws + 86400000);     //    400,000
    int* row_start   = (int*)(ws + 86800000);     //    400,004
    int* cursor      = (int*)(ws + 87200256);     //    400,000
    int* partial     = (int*)(ws + 87600256);     //        512
    // total ~87.6 MB

    hipMemsetAsync(cnt, 0, N_NODES * sizeof(int), stream);
    k_gemm<<<(N_NODES + 63) / 64, 256, 0, stream>>>(x, W, xp);
    k_attdots<<<(N_NODES * HEADS + 255) / 256, 256, 0, stream>>>(xp, att_src, att_dst, asrc, adst);
    k_count<<<(N_EDGES + 255) / 256, 256, 0, stream>>>(ei, cnt);
    k_scan1<<<SCAN_NBLK, 256, 0, stream>>>(cnt, row_start, partial);
    k_scan2<<<1, 128, 0, stream>>>(partial);
    k_scan3<<<(N_NODES + 255) / 256, 256, 0, stream>>>(row_start, partial, cursor);
    k_scatter<<<(N_EDGES + 255) / 256, 256, 0, stream>>>(ei, (const float4*)asrc, (const float4*)adst, cursor, esrc, att4);
    k_aggregate<<<(N_NODES + 3) / 4, 256, 0, stream>>>(row_start, esrc, att4, xp, bias, out);
}

// Round 3
// 297.705 us; speedup vs baseline: 1.5665x; 1.1732x over previous
//
#include <hip/hip_runtime.h>
#include <math.h>

#define N_NODES 100000
#define N_EDGES 1600000
#define IN_DIM 128
#define HEADS 4
#define OUT_DIM 32
#define HD 128  // HEADS*OUT_DIM
#define NEG_SLOPE 0.2f
#define SCAN_NBLK 98  // ceil(100000/1024)

typedef __attribute__((ext_vector_type(8))) short short8;
typedef __attribute__((ext_vector_type(4))) float f32x4;

__device__ inline ushort f2bf(float f) {
    // round-to-nearest-even fp32 -> bf16
    uint u = __float_as_uint(f);
    u += 0x7fffu + ((u >> 16) & 1u);
    return (ushort)(u >> 16);
}
__device__ inline float bf2f(ushort h) {
    return __uint_as_float(((uint)h) << 16);
}

// ---------------- K1: x_proj = x @ W^T  (bf16 MFMA, fused att-dots) ----------------
// Block: 256 threads (4 waves). Tile: 64 rows x 128 cols, K=128.
// LDS: lA = 64x128 bf16 A-tile (reused as out-tile), lB = 128x128 bf16 W-tile.
// Both XOR-swizzled (byte ^= (row&7)<<4) so ds_read_b128 fragments are ~conflict-free.
__global__ __launch_bounds__(256) void k_gemm(const float* __restrict__ x,
                                              const float* __restrict__ W,
                                              ushort* __restrict__ xp,
                                              const float* __restrict__ att_src,
                                              const float* __restrict__ att_dst,
                                              float* __restrict__ asrc,
                                              float* __restrict__ adst) {
    __shared__ ushort lA[64 * 128];   // 16 KB
    __shared__ ushort lB[128 * 128];  // 32 KB
    const int tid = threadIdx.x;
    const long row_base = (long)blockIdx.x * 64;

    // ---- stage A (x rows, fp32 -> bf16, swizzled) ----
    {
        const int r = tid >> 2;
        const int c0 = (tid & 3) * 32;
        const long row = row_base + r;
        const float* src = x + row * IN_DIM + c0;
#pragma unroll
        for (int i = 0; i < 4; i++) {  // 8 cols per iter
            float4 va, vb;
            if (row < N_NODES) {
                va = *(const float4*)(src + 8 * i);
                vb = *(const float4*)(src + 8 * i + 4);
            } else {
                va = make_float4(0.f, 0.f, 0.f, 0.f);
                vb = va;
            }
            ushort h[8] = {f2bf(va.x), f2bf(va.y), f2bf(va.z), f2bf(va.w),
                           f2bf(vb.x), f2bf(vb.y), f2bf(vb.z), f2bf(vb.w)};
            uint byte = (uint)(r * 256 + (c0 + 8 * i) * 2);
            byte ^= (uint)((r & 7) << 4);
            *(uint4*)((char*)lA + byte) = *(const uint4*)h;
        }
    }
    // ---- stage B (W rows, fp32 -> bf16, swizzled): lB[c][k] = W[c][k] ----
    {
        const int c = tid >> 1;
        const int k0 = (tid & 1) * 64;
        const float* src = W + c * IN_DIM + k0;
#pragma unroll
        for (int i = 0; i < 8; i++) {  // 8 k per iter
            float4 va = *(const float4*)(src + 8 * i);
            float4 vb = *(const float4*)(src + 8 * i + 4);
            ushort h[8] = {f2bf(va.x), f2bf(va.y), f2bf(va.z), f2bf(va.w),
                           f2bf(vb.x), f2bf(vb.y), f2bf(vb.z), f2bf(vb.w)};
            uint byte = (uint)(c * 256 + (k0 + 8 * i) * 2);
            byte ^= (uint)((c & 7) << 4);
            *(uint4*)((char*)lB + byte) = *(const uint4*)h;
        }
    }
    __syncthreads();

    // ---- MFMA main: wave w owns rows w*16..w*16+15, all 128 cols ----
    const int w = tid >> 6;
    const int lane = tid & 63;
    const int l15 = lane & 15;
    const int g8 = (lane >> 4) * 8;  // k sub-offset (consistent convention for A and B)
    const int arow = w * 16 + l15;

    f32x4 acc[8];
#pragma unroll
    for (int nt = 0; nt < 8; nt++) acc[nt] = (f32x4){0.f, 0.f, 0.f, 0.f};

#pragma unroll
    for (int t = 0; t < 4; t++) {
        uint ab = (uint)(arow * 256 + (t * 32 + g8) * 2);
        ab ^= (uint)((arow & 7) << 4);
        short8 af = *(const short8*)((const char*)lA + ab);
#pragma unroll
        for (int nt = 0; nt < 8; nt++) {
            int c = nt * 16 + l15;
            uint bb = (uint)(c * 256 + (t * 32 + g8) * 2);
            bb ^= (uint)((c & 7) << 4);
            short8 bfr = *(const short8*)((const char*)lB + bb);
            acc[nt] = __builtin_amdgcn_mfma_f32_16x16x32_bf16(af, bfr, acc[nt], 0, 0, 0);
        }
    }
    __syncthreads();  // done reading lA/lB; reuse lA as out-tile

    // ---- write acc -> lA (linear [64][128] bf16 out-tile) ----
    // C/D layout: col = lane&15, row = 4*(lane>>4)+reg  [m89/m91]
    {
        const int m4 = 4 * (lane >> 4);
#pragma unroll
        for (int nt = 0; nt < 8; nt++) {
            int c = nt * 16 + l15;
#pragma unroll
            for (int r = 0; r < 4; r++) {
                lA[(w * 16 + m4 + r) * 128 + c] = f2bf(acc[nt][r]);
            }
        }
    }
    __syncthreads();

    // ---- epilogue: coalesced xp store + fused attention dots ----
    {
        const int r = tid >> 2;
        const long node = row_base + r;
        if (node < N_NODES) {
            const int h = tid & 3;
            const int c0 = h * 32;
            const uint4* s = (const uint4*)(lA + r * 128 + c0);
            uint4 v0 = s[0], v1 = s[1], v2 = s[2], v3 = s[3];
            uint4* d = (uint4*)(xp + node * HD + c0);
            d[0] = v0; d[1] = v1; d[2] = v2; d[3] = v3;
            // att dots over this head's 32 cols (values already in regs)
            const float* as = att_src + c0;
            const float* ad = att_dst + c0;
            float s0 = 0.f, s1 = 0.f;
            uint4 vv[4] = {v0, v1, v2, v3};
#pragma unroll
            for (int q = 0; q < 4; q++) {
                const uint* u = (const uint*)&vv[q];
#pragma unroll
                for (int p = 0; p < 4; p++) {
                    float f0 = __uint_as_float((u[p] & 0xffffu) << 16);
                    float f1 = __uint_as_float(u[p] & 0xffff0000u);
                    int cc = q * 8 + p * 2;
                    s0 = fmaf(f0, as[cc], s0);
                    s0 = fmaf(f1, as[cc + 1], s0);
                    s1 = fmaf(f0, ad[cc], s1);
                    s1 = fmaf(f1, ad[cc + 1], s1);
                }
            }
            asrc[node * HEADS + h] = s0;
            adst[node * HEADS + h] = s1;
        }
    }
}

// ---------------- K2: per-dst edge counts ----------------
__global__ void k_count(const int* __restrict__ ei, int* __restrict__ cnt) {
    int e = blockIdx.x * 256 + threadIdx.x;
    if (e < N_EDGES) atomicAdd(&cnt[ei[N_EDGES + e]], 1);
}

// ---------------- K3: exclusive scan of counts (3 kernels) ----------------
__global__ __launch_bounds__(256) void k_scan1(const int* __restrict__ cnt,
                                               int* __restrict__ row_start,
                                               int* __restrict__ partial) {
    __shared__ int lds[256];
    int t = threadIdx.x;
    int base = blockIdx.x * 1024 + t * 4;
    int c0 = (base + 0 < N_NODES) ? cnt[base + 0] : 0;
    int c1 = (base + 1 < N_NODES) ? cnt[base + 1] : 0;
    int c2 = (base + 2 < N_NODES) ? cnt[base + 2] : 0;
    int c3 = (base + 3 < N_NODES) ? cnt[base + 3] : 0;
    int p1 = c0, p2 = c0 + c1, p3 = c0 + c1 + c2;
    int tsum = p3 + c3;
    lds[t] = tsum;
    __syncthreads();
    for (int off = 1; off < 256; off <<= 1) {
        int v = (t >= off) ? lds[t - off] : 0;
        __syncthreads();
        lds[t] += v;
        __syncthreads();
    }
    int excl = (t == 0) ? 0 : lds[t - 1];
    if (base + 0 < N_NODES) row_start[base + 0] = excl;
    if (base + 1 < N_NODES) row_start[base + 1] = excl + p1;
    if (base + 2 < N_NODES) row_start[base + 2] = excl + p2;
    if (base + 3 < N_NODES) row_start[base + 3] = excl + p3;
    if (t == 255) partial[blockIdx.x] = lds[255];
}

__global__ __launch_bounds__(128) void k_scan2(int* __restrict__ partial) {
    __shared__ int lds[128];
    int t = threadIdx.x;
    int v = (t < SCAN_NBLK) ? partial[t] : 0;
    lds[t] = v;
    __syncthreads();
    for (int off = 1; off < 128; off <<= 1) {
        int u = (t >= off) ? lds[t - off] : 0;
        __syncthreads();
        lds[t] += u;
        __syncthreads();
    }
    if (t < SCAN_NBLK) partial[t] = (t == 0) ? 0 : lds[t - 1];
}

__global__ void k_scan3(int* __restrict__ row_start, const int* __restrict__ partial,
                        int* __restrict__ cursor) {
    int i = blockIdx.x * 256 + threadIdx.x;
    if (i < N_NODES) {
        int rs = row_start[i] + partial[i >> 10];
        row_start[i] = rs;
        cursor[i] = rs;
    }
    if (i == 0) row_start[N_NODES] = N_EDGES;
}

// ---------------- K4: attention logits + CSR scatter ----------------
__global__ void k_scatter(const int* __restrict__ ei,
                          const float4* __restrict__ asrc4,
                          const float4* __restrict__ adst4,
                          int* __restrict__ cursor,
                          int* __restrict__ esrc,
                          float4* __restrict__ att4) {
    int e = blockIdx.x * 256 + threadIdx.x;
    if (e >= N_EDGES) return;
    int s = ei[e];
    int d = ei[N_EDGES + e];
    float4 a = asrc4[s];
    float4 b = adst4[d];
    float4 t;
    t.x = a.x + b.x; t.y = a.y + b.y; t.z = a.z + b.z; t.w = a.w + b.w;
    t.x = (t.x >= 0.f) ? t.x : NEG_SLOPE * t.x;
    t.y = (t.y >= 0.f) ? t.y : NEG_SLOPE * t.y;
    t.z = (t.z >= 0.f) ? t.z : NEG_SLOPE * t.z;
    t.w = (t.w >= 0.f) ? t.w : NEG_SLOPE * t.w;
    int pos = atomicAdd(&cursor[d], 1);
    esrc[pos] = s;
    att4[pos] = t;
}

// ---------------- K5: single-pass softmax + aggregation (1 wave/node) ----------------
// xp is bf16; lane owns output elements {2*lane, 2*lane+1} (same head h=lane>>4),
// so each edge's row gather is ONE ushort2-per-lane load (256 B/wave = 1 row).
// Unnormalized exp (shift-invariant softmax; logits bounded, clamp 80).
__global__ __launch_bounds__(256) void k_aggregate(const int* __restrict__ row_start,
                                                   const int* __restrict__ esrc,
                                                   const float4* __restrict__ att4,
                                                   const ushort* __restrict__ xp,
                                                   const float* __restrict__ bias,
                                                   float* __restrict__ out) {
    const int wid = threadIdx.x >> 6;
    const int lane = threadIdx.x & 63;
    const int n = blockIdx.x * 4 + wid;
    if (n >= N_NODES) return;
    const int s0 = row_start[n];
    const int s1 = row_start[n + 1];
    const int h = lane >> 4;

    float acc0 = 0.f, acc1 = 0.f, den = 0.f;

    for (int base = s0; base < s1; base += 64) {
        const int rem = s1 - base;
        const int cnt = rem < 64 ? rem : 64;
        const bool v = lane < cnt;
        int msrc = v ? esrc[base + lane] : 0;
        float4 ma = v ? att4[base + lane] : make_float4(-1e30f, -1e30f, -1e30f, -1e30f);
        float wx = __expf(fminf(ma.x, 80.f));
        float wy = __expf(fminf(ma.y, 80.f));
        float wz = __expf(fminf(ma.z, 80.f));
        float ww = __expf(fminf(ma.w, 80.f));

        int j = 0;
        for (; j + 4 <= cnt; j += 4) {
            const uint* p[4];
            float ee[4];
#pragma unroll
            for (int u = 0; u < 4; u++) {
                int src = __shfl(msrc, j + u);
                float a = __shfl(wx, j + u);
                float b = __shfl(wy, j + u);
                float c = __shfl(wz, j + u);
                float d = __shfl(ww, j + u);
                float lo = (h & 1) ? b : a;
                float hi = (h & 1) ? d : c;
                ee[u] = (h & 2) ? hi : lo;
                p[u] = (const uint*)(xp + (long)src * HD) + lane;
            }
            uint g[4];
#pragma unroll
            for (int u = 0; u < 4; u++) g[u] = *p[u];
#pragma unroll
            for (int u = 0; u < 4; u++) {
                float f0 = __uint_as_float((g[u] & 0xffffu) << 16);
                float f1 = __uint_as_float(g[u] & 0xffff0000u);
                den += ee[u];
                acc0 = fmaf(ee[u], f0, acc0);
                acc1 = fmaf(ee[u], f1, acc1);
            }
        }
        for (; j < cnt; j++) {
            int src = __shfl(msrc, j);
            float a = __shfl(wx, j);
            float b = __shfl(wy, j);
            float c = __shfl(wz, j);
            float d = __shfl(ww, j);
            float lo = (h & 1) ? b : a;
            float hi = (h & 1) ? d : c;
            float e = (h & 2) ? hi : lo;
            uint g = *((const uint*)(xp + (long)src * HD) + lane);
            float f0 = __uint_as_float((g & 0xffffu) << 16);
            float f1 = __uint_as_float(g & 0xffff0000u);
            den += e;
            acc0 = fmaf(e, f0, acc0);
            acc1 = fmaf(e, f1, acc1);
        }
    }
    float inv = 1.f / (den + 1e-12f);
    float2 b2 = ((const float2*)bias)[lane];
    float2 o;
    o.x = acc0 * inv + b2.x;
    o.y = acc1 * inv + b2.y;
    ((float2*)(out + (long)n * HD))[lane] = o;
}

extern "C" void kernel_launch(void* const* d_in, const int* in_sizes, int n_in,
                              void* d_out, int out_size, void* d_ws, size_t ws_size,
                              hipStream_t stream) {
    const float* x = (const float*)d_in[0];
    const int* ei = (const int*)d_in[1];
    const float* W = (const float*)d_in[2];
    const float* att_src = (const float*)d_in[3];
    const float* att_dst = (const float*)d_in[4];
    const float* bias = (const float*)d_in[5];
    float* out = (float*)d_out;
    char* ws = (char*)d_ws;

    // workspace layout (bytes), 16B-aligned
    ushort* xp       = (ushort*)(ws + 0);         // 25,600,000 (bf16 x_proj)
    float* asrc      = (float*)(ws + 25600000);   //  1,600,000
    float* adst      = (float*)(ws + 27200000);   //  1,600,000
    float4* att4     = (float4*)(ws + 28800000);  // 25,600,000
    int* esrc        = (int*)(ws + 54400000);     //  6,400,000
    int* cnt         = (int*)(ws + 60800000);     //    400,000
    int* row_start   = (int*)(ws + 61200000);     //    400,004
    int* cursor      = (int*)(ws + 61600016);     //    400,000
    int* partial     = (int*)(ws + 62000016);     //        512
    // total ~62 MB

    hipMemsetAsync(cnt, 0, N_NODES * sizeof(int), stream);
    k_gemm<<<(N_NODES + 63) / 64, 256, 0, stream>>>(x, W, xp, att_src, att_dst, asrc, adst);
    k_count<<<(N_EDGES + 255) / 256, 256, 0, stream>>>(ei, cnt);
    k_scan1<<<SCAN_NBLK, 256, 0, stream>>>(cnt, row_start, partial);
    k_scan2<<<1, 128, 0, stream>>>(partial);
    k_scan3<<<(N_NODES + 255) / 256, 256, 0, stream>>>(row_start, partial, cursor);
    k_scatter<<<(N_EDGES + 255) / 256, 256, 0, stream>>>(ei, (const float4*)asrc, (const float4*)adst, cursor, esrc, att4);
    k_aggregate<<<(N_NODES + 3) / 4, 256, 0, stream>>>(row_start, esrc, att4, xp, bias, out);
}